// Round 6
// baseline (168.664 us; speedup 1.0000x reference)
//
#include <hip/hip_runtime.h>

// HSTU attention layer: B=2, L=2048, D=1024, H=16, DK=64
// Pipeline: fp32->bf16 cvt (W_q pre-scaled by 0.125*log2e) -> QKVU GEMM ->
// V-transpose (swizzled tile images) -> flash HSTU attention (swapped 32x32x16,
// no-max softmax, MFMA row-sum, 3-deep async staging, counted vmcnt) ->
// gated bf16 -> out GEMM.

#define L_SEQ 2048

typedef __attribute__((ext_vector_type(8))) short bf16x8;     // MFMA A/B frag
typedef __attribute__((ext_vector_type(8))) unsigned short u16x8;
typedef __attribute__((ext_vector_type(4))) float f32x4;      // 16x16 C/D frag
typedef __attribute__((ext_vector_type(16))) float f32x16;    // 32x32 C/D frag

__device__ __forceinline__ unsigned short f2bf(float f) {
  union { float f; unsigned u; } c; c.f = f;
  unsigned r = c.u + 0x7FFFu + ((c.u >> 16) & 1u);   // RNE
  return (unsigned short)(r >> 16);
}
__device__ __forceinline__ float bf2f(unsigned short h) {
  union { unsigned u; float f; } c; c.u = ((unsigned)h) << 16;
  return c.f;
}

// async global->LDS, 16B/lane. LDS dest = wave-uniform base + lane*16 (linear).
__device__ __forceinline__ void async16(const void* g, void* l) {
  __builtin_amdgcn_global_load_lds((__attribute__((address_space(1))) void*)g,
                                   (__attribute__((address_space(3))) void*)l,
                                   16, 0, 0);
}

__device__ __forceinline__ unsigned cvtpk_bf16(float lo, float hi) {
  unsigned r; asm("v_cvt_pk_bf16_f32 %0, %1, %2" : "=v"(r) : "v"(lo), "v"(hi));
  return r;
}

// ---------------- fp32 -> bf16 convert (x) ----------------
__global__ __launch_bounds__(256) void cvt_kernel(const float* __restrict__ s,
                                                  unsigned short* __restrict__ d, int n) {
  int i = (blockIdx.x * 256 + threadIdx.x) * 4;
  if (i >= n) return;
  const float4 v = *reinterpret_cast<const float4*>(s + i);
  ushort4 o;
  o.x = f2bf(v.x); o.y = f2bf(v.y); o.z = f2bf(v.z); o.w = f2bf(v.w);
  *reinterpret_cast<ushort4*>(d + i) = o;
}

// ---------------- fused weight convert: Wq(scaled)|Wk|Wv|Wu|Wo -> bf16 ------
__global__ __launch_bounds__(256) void cvtw_kernel(
    const float* __restrict__ wq, const float* __restrict__ wk,
    const float* __restrict__ wv, const float* __restrict__ wu,
    const float* __restrict__ wo, unsigned short* __restrict__ d) {
  const int seg = blockIdx.x >> 10;                  // 1024 blocks per 1M-elem segment
  const float* s = seg == 0 ? wq : seg == 1 ? wk : seg == 2 ? wv : seg == 3 ? wu : wo;
  const float sc = seg == 0 ? 0.18033688011112042f : 1.0f;   // 0.125 * log2(e)
  const int i = ((blockIdx.x & 1023) * 256 + threadIdx.x) * 4;
  const float4 v = *reinterpret_cast<const float4*>(s + i);
  ushort4 o;
  o.x = f2bf(v.x * sc); o.y = f2bf(v.y * sc); o.z = f2bf(v.z * sc); o.w = f2bf(v.w * sc);
  *reinterpret_cast<ushort4*>(d + (size_t)seg * 1048576 + i) = o;
}

// ---------------- key "always-allowed" bitmask: (prompt && j<seqlen) --------
__global__ __launch_bounds__(64) void maskbuild(const int* __restrict__ tt,
                                                const int* __restrict__ sl,
                                                unsigned* __restrict__ allowed) {
  const int b = blockIdx.x >> 5, wv = blockIdx.x & 31;
  const int j = wv * 64 + threadIdx.x;
  const int seqlen = sl[b];
  const unsigned long long m = __ballot((tt[b * L_SEQ + j] < 3) && (j < seqlen));
  if (threadIdx.x == 0) {
    allowed[b * 64 + 2 * wv]     = (unsigned)m;
    allowed[b * 64 + 2 * wv + 1] = (unsigned)(m >> 32);
  }
}

// ---------------- V transpose into swizzled tile images ---------------------
// vtg layout: per (b,h,tile t): 4096 elems (8KB) = the exact LDS image attn
// wants: element (k local, d) at byte d*128 + 16*((k>>3)^(d&7)) + 2*(k&7).
__global__ __launch_bounds__(256) void vtrans(const unsigned short* __restrict__ qkvu,
                                              unsigned short* __restrict__ vtg) {
  __shared__ unsigned short tileb[4096];
  const int t = blockIdx.x, h = blockIdx.y, b = blockIdx.z;
  const size_t rb = (size_t)b * L_SEQ * 4096;
  const int tid = threadIdx.x;
  const int vp = tid & 31, vd0 = (tid >> 5) * 8;
  const int j0 = t * 64;
  const u16x8 g0 = *reinterpret_cast<const u16x8*>(
      qkvu + rb + (size_t)(j0 + 2 * vp) * 4096 + 2048 + h * 64 + vd0);
  const u16x8 g1 = *reinterpret_cast<const u16x8*>(
      qkvu + rb + (size_t)(j0 + 2 * vp + 1) * 4096 + 2048 + h * 64 + vd0);
  #pragma unroll
  for (int e = 0; e < 8; ++e) {
    const int d = vd0 + e;
    const unsigned pk = (unsigned)g0[e] | ((unsigned)g1[e] << 16);
    *reinterpret_cast<unsigned*>((char*)tileb +
        d * 128 + 16 * ((vp >> 2) ^ (d & 7)) + 4 * (vp & 3)) = pk;
  }
  __syncthreads();
  const size_t ob = ((size_t)(b * 16 + h) * 32 + t) * 4096;
  *reinterpret_cast<u16x8*>(vtg + ob + tid * 16) =
      *reinterpret_cast<const u16x8*>(tileb + tid * 16);
  *reinterpret_cast<u16x8*>(vtg + ob + tid * 16 + 8) =
      *reinterpret_cast<const u16x8*>(tileb + tid * 16 + 8);
}

// ---------------- GEMM: C[M][N] = A[M][K] * BT[N][K]^T (m97 structure) -------
template<int OUT_BF16>
__global__ __launch_bounds__(256) void gemm_bt(
    const unsigned short* __restrict__ A,
    const unsigned short* __restrict__ BT,
    float* __restrict__ Cf, unsigned short* __restrict__ Cb,
    int M, int N, int K)
{
  __shared__ unsigned short As[2][128 * 32];
  __shared__ unsigned short Bs[2][128 * 32];

  const int tid = threadIdx.x;
  const int w = tid >> 6, lane = tid & 63;
  const int lo = lane & 15, hi = lane >> 4;
  const int i0 = blockIdx.y * 128, j0 = blockIdx.x * 128;
  const int wr = w >> 1, wc = w & 1;
  const int c0 = w * 2, rsub = lane >> 2, csub = (lane & 3) * 8;

  f32x4 acc[4][4] = {};

  #pragma unroll
  for (int q = 0; q < 2; ++q) {
    const int c = c0 + q;
    async16(A  + (size_t)(i0 + c * 16 + rsub) * K + csub, &As[0][c * 512]);
    async16(BT + (size_t)(j0 + c * 16 + rsub) * K + csub, &Bs[0][c * 512]);
  }
  __syncthreads();

  const int nt = K >> 5;
  for (int t = 0; t < nt; ++t) {
    const int buf = t & 1;
    if (t + 1 < nt) {
      const int k0 = (t + 1) << 5;
      #pragma unroll
      for (int q = 0; q < 2; ++q) {
        const int c = c0 + q;
        async16(A  + (size_t)(i0 + c * 16 + rsub) * K + k0 + csub, &As[buf ^ 1][c * 512]);
        async16(BT + (size_t)(j0 + c * 16 + rsub) * K + k0 + csub, &Bs[buf ^ 1][c * 512]);
      }
    }
    bf16x8 a[4], b[4];
    #pragma unroll
    for (int m = 0; m < 4; ++m)
      a[m] = *reinterpret_cast<const bf16x8*>(&As[buf][(wr * 64 + m * 16 + lo) * 32 + hi * 8]);
    #pragma unroll
    for (int n = 0; n < 4; ++n)
      b[n] = *reinterpret_cast<const bf16x8*>(&Bs[buf][(wc * 64 + n * 16 + lo) * 32 + hi * 8]);
    #pragma unroll
    for (int m = 0; m < 4; ++m)
      #pragma unroll
      for (int n = 0; n < 4; ++n)
        acc[m][n] = __builtin_amdgcn_mfma_f32_16x16x32_bf16(a[m], b[n], acc[m][n], 0, 0, 0);
    __syncthreads();
  }

  #pragma unroll
  for (int m = 0; m < 4; ++m) {
    const int row = i0 + wr * 64 + m * 16 + hi * 4;
    #pragma unroll
    for (int n = 0; n < 4; ++n) {
      const int col = j0 + wc * 64 + n * 16 + lo;
      #pragma unroll
      for (int r = 0; r < 4; ++r) {
        if (OUT_BF16) Cb[(size_t)(row + r) * N + col] = f2bf(acc[m][n][r]);
        else          Cf[(size_t)(row + r) * N + col] = acc[m][n][r];
      }
    }
  }
}

// ---------------- HSTU flash attention + U gating (32x32 swapped) -----------
// grid (L/128, H, B), 256 threads (4 waves), wave w owns q-rows i0+w*32..+31.
// 3-deep async16 staging for K (from qkvu) and V^T (from vtg), counted vmcnt,
// raw barriers (no vmcnt(0) drain). Lane (c=lane&31) owns q-row i0+w*32+c.
__global__ __launch_bounds__(256) void hstu_attn(
    const unsigned short* __restrict__ qkvu,
    const unsigned short* __restrict__ vtg,
    const unsigned* __restrict__ allowed,
    const int* __restrict__ slens,
    unsigned short* __restrict__ gated)
{
  // K: [64 key][64 d] row-major, XOR-swizzled: byte = k*128 + 16*((d>>3)^(k&7)) + 2*(d&7)
  // Vl: V^T tile image: element (k,d) at byte d*128 + 16*((k>>3)^(d&7)) + 2*(k&7)
  __shared__ unsigned short Kl[3][64 * 64];
  __shared__ unsigned short Vl[3][64 * 64];

  const int qt = blockIdx.x, h = blockIdx.y, b = blockIdx.z;
  const int i0 = qt * 128;
  const int tid = threadIdx.x, w = tid >> 6, lane = tid & 63;
  const int c = lane & 31, sb = lane >> 5;
  const int seqlen = slens[b];
  const size_t rb = (size_t)b * L_SEQ * 4096;
  const size_t vb = (size_t)(b * 16 + h) * 32 * 4096;
  const int qrow = i0 + w * 32 + c;

  // K staging: pre-swizzled global source, linear LDS dest (2 async16/wave).
  auto stageK = [&](int buf, int t) {
    const int j0 = t * 64;
    #pragma unroll
    for (int q = 0; q < 2; ++q) {
      const int p = w * 2 + q;                       // window 0..7 (8 keys each)
      const int krow = 8 * p + (lane >> 3);
      const int d0 = 8 * ((lane & 7) ^ (lane >> 3)); // inverse of read swizzle
      async16(qkvu + rb + (size_t)(j0 + krow) * 4096 + 1024 + h * 64 + d0,
              &Kl[buf][p * 512]);
    }
  };
  // V^T staging: tile image is already swizzled in global — linear copy (2/wave).
  auto stageV = [&](int buf, int t) {
    #pragma unroll
    for (int q = 0; q < 2; ++q) {
      const int p = w * 2 + q;
      async16(vtg + vb + (size_t)t * 4096 + p * 512 + lane * 8, &Vl[buf][p * 512]);
    }
  };

  const int nt = (seqlen + 63) >> 6;

  // prologue: stage tiles 0,1; load Q frags, mask word; full drain once.
  stageK(0, 0); stageV(0, 0);
  stageK(1, 1); stageV(1, 1);

  bf16x8 qf[4];
  #pragma unroll
  for (int kd = 0; kd < 4; ++kd)
    qf[kd] = *reinterpret_cast<const bf16x8*>(
        qkvu + rb + (size_t)qrow * 4096 + h * 64 + kd * 16 + sb * 8);
  const unsigned pmword = allowed[b * 64 + lane];

  union { unsigned u[4]; bf16x8 v; } one_;
  one_.u[0] = one_.u[1] = one_.u[2] = one_.u[3] = 0x3F803F80u;
  const bf16x8 onesv = one_.v;

  f32x16 o0 = {}, o1 = {}, ls = {};

  asm volatile("s_waitcnt vmcnt(0)" ::: "memory");
  __builtin_amdgcn_s_barrier();
  __builtin_amdgcn_sched_barrier(0);

  for (int t = 0; t < nt; ++t) {
    const int buf = t % 3;
    const int j0 = t * 64;
    // issue prefetch for t+2 (buffer (t+2)%3 — safe: all waves passed the
    // barrier, so tile t-1 reads of that buffer are complete)
    if (t + 2 < nt) { const int nb = (t + 2) % 3; stageK(nb, t + 2); stageV(nb, t + 2); }

    // ---- QK^T (swapped): S^T[key][q]; s0: keys j0..+31, s1: +32..+63 ----
    f32x16 s0 = {}, s1 = {};
    #pragma unroll
    for (int kd = 0; kd < 4; ++kd) {
      const int sw = ((2 * kd + sb) ^ (c & 7)) << 4;
      bf16x8 k0 = *reinterpret_cast<const bf16x8*>((const char*)&Kl[buf][0] + c * 128 + sw);
      bf16x8 k1 = *reinterpret_cast<const bf16x8*>((const char*)&Kl[buf][0] + (32 + c) * 128 + sw);
      s0 = __builtin_amdgcn_mfma_f32_32x32x16_bf16(k0, qf[kd], s0, 0, 0, 0);
      s1 = __builtin_amdgcn_mfma_f32_32x32x16_bf16(k1, qf[kd], s1, 0, 0, 0);
    }

    // ---- exp + mask (lane-local). Scores pre-scaled; exp2 directly. ----
    if ((j0 + 64 <= seqlen) && (j0 + 63 <= i0 + w * 32)) {
      #pragma unroll
      for (int r = 0; r < 16; ++r) {
        s0[r] = __builtin_exp2f(s0[r]);
        s1[r] = __builtin_exp2f(s1[r]);
      }
    } else {
      const unsigned pmA = __builtin_amdgcn_readlane(pmword, 2 * t);
      const unsigned pmB = __builtin_amdgcn_readlane(pmword, 2 * t + 1);
      const int sh = 4 * sb;
      const int limq = (qrow < seqlen - 1 ? qrow : seqlen - 1) - j0 - sh;
      const int lim0 = limq, lim1 = limq - 32;
      const unsigned cm0 = lim0 < 0 ? 0u : (lim0 >= 31 ? ~0u : ((2u << lim0) - 1u));
      const unsigned cm1 = lim1 < 0 ? 0u : (lim1 >= 31 ? ~0u : ((2u << lim1) - 1u));
      const unsigned al0 = (pmA >> sh) | cm0;
      const unsigned al1 = (pmB >> sh) | cm1;
      #pragma unroll
      for (int r = 0; r < 16; ++r) {
        const int kc = (r & 3) + 8 * (r >> 2);       // key pos (minus 4*sb)
        float p0 = __builtin_exp2f(s0[r]);
        float p1 = __builtin_exp2f(s1[r]);
        s0[r] = ((al0 >> kc) & 1) ? p0 : 0.f;
        s1[r] = ((al1 >> kc) & 1) ? p1 : 0.f;
      }
    }

    // ---- P pack to bf16 B-frags: 16 cvt_pk + 8 permlane32_swap (T12) ----
    bf16x8 pf[4];
    #pragma unroll
    for (int kp = 0; kp < 4; ++kp) {
      const int a0 = 8 * (kp & 1);
      unsigned U0, U1, W0, W1;
      if (kp < 2) {
        U0 = cvtpk_bf16(s0[a0 + 0], s0[a0 + 1]); U1 = cvtpk_bf16(s0[a0 + 2], s0[a0 + 3]);
        W0 = cvtpk_bf16(s0[a0 + 4], s0[a0 + 5]); W1 = cvtpk_bf16(s0[a0 + 6], s0[a0 + 7]);
      } else {
        U0 = cvtpk_bf16(s1[a0 + 0], s1[a0 + 1]); U1 = cvtpk_bf16(s1[a0 + 2], s1[a0 + 3]);
        W0 = cvtpk_bf16(s1[a0 + 4], s1[a0 + 5]); W1 = cvtpk_bf16(s1[a0 + 6], s1[a0 + 7]);
      }
      asm volatile("v_permlane32_swap_b32 %0, %1" : "+v"(U0), "+v"(W0));
      asm volatile("v_permlane32_swap_b32 %0, %1" : "+v"(U1), "+v"(W1));
      union { unsigned u[4]; bf16x8 v; } pu;
      pu.u[0] = U0; pu.u[1] = U1; pu.u[2] = W0; pu.u[3] = W1;
      pf[kp] = pu.v;
    }

    // ---- PV (swapped): O^T[d][q] += V^T x P ; lsum via ones-MFMA ----
    #pragma unroll
    for (int kp = 0; kp < 4; ++kp) {
      const int vsw = ((2 * kp + sb) ^ (c & 7)) << 4;
      bf16x8 v0 = *reinterpret_cast<const bf16x8*>((const char*)&Vl[buf][0] + c * 128 + vsw);
      bf16x8 v1 = *reinterpret_cast<const bf16x8*>((const char*)&Vl[buf][0] + (32 + c) * 128 + vsw);
      o0 = __builtin_amdgcn_mfma_f32_32x32x16_bf16(v0, pf[kp], o0, 0, 0, 0);
      o1 = __builtin_amdgcn_mfma_f32_32x32x16_bf16(v1, pf[kp], o1, 0, 0, 0);
      ls = __builtin_amdgcn_mfma_f32_32x32x16_bf16(onesv, pf[kp], ls, 0, 0, 0);
    }

    // counted vmcnt: only stage(t+2)'s 4 ops may remain outstanding -> t+1 landed
    asm volatile("s_waitcnt vmcnt(4)" ::: "memory");
    __builtin_amdgcn_s_barrier();
    __builtin_amdgcn_sched_barrier(0);
  }

  // ---- epilogue: gated = O/l * U ; O^T row d = n*32+(r&3)+8*(r>>2)+4sb, col q ----
  const float rin = 1.0f / ls[0];
  #pragma unroll
  for (int n = 0; n < 2; ++n) {
    const f32x16 o = n ? o1 : o0;
    #pragma unroll
    for (int rq = 0; rq < 4; ++rq) {
      const int d0 = n * 32 + 8 * rq + 4 * sb;
      const ushort4 uu = *reinterpret_cast<const ushort4*>(
          qkvu + rb + (size_t)qrow * 4096 + 3072 + h * 64 + d0);
      ushort4 g;
      g.x = f2bf(o[4 * rq + 0] * rin * bf2f(uu.x));
      g.y = f2bf(o[4 * rq + 1] * rin * bf2f(uu.y));
      g.z = f2bf(o[4 * rq + 2] * rin * bf2f(uu.z));
      g.w = f2bf(o[4 * rq + 3] * rin * bf2f(uu.w));
      *reinterpret_cast<ushort4*>(
          gated + (size_t)(b * L_SEQ + qrow) * 1024 + h * 64 + d0) = g;
    }
  }
}

// ---------------- launch ----------------
extern "C" void kernel_launch(void* const* d_in, const int* in_sizes, int n_in,
                              void* d_out, int out_size, void* d_ws, size_t ws_size,
                              hipStream_t stream) {
  const float* x  = (const float*)d_in[0];
  const int* tt   = (const int*)d_in[1];
  const int* sl   = (const int*)d_in[2];
  const float* Wq = (const float*)d_in[3];
  const float* Wk = (const float*)d_in[4];
  const float* Wv = (const float*)d_in[5];
  const float* Wu = (const float*)d_in[6];
  const float* Wo = (const float*)d_in[7];
  float* out = (float*)d_out;

  // ws layout: allowed[512B] | xb(8MB, ->vtg after GEMM1) | wcat(8MB) |
  //            wob(2MB) | qkvu(32MB) | gated(8MB)
  unsigned* allowed     = (unsigned*)d_ws;
  unsigned short* xb    = (unsigned short*)d_ws + 256;
  unsigned short* wcat  = xb    + (size_t)4096 * 1024;
  unsigned short* wob   = wcat  + (size_t)4096 * 1024;
  unsigned short* qkvu  = wob   + (size_t)1024 * 1024;
  unsigned short* gated = qkvu  + (size_t)4096 * 4096;
  unsigned short* vtg   = xb;    // 8MB, reuses xb AFTER GEMM1 consumed it

  cvt_kernel<<<4096, 256, 0, stream>>>(x, xb, 4096 * 1024);
  cvtw_kernel<<<5120, 256, 0, stream>>>(Wq, Wk, Wv, Wu, Wo, wcat);

  // QKVU = x @ [Wq'|Wk|Wv|Wu]^T   (M=4096, N=4096, K=1024)
  gemm_bt<1><<<dim3(32, 32), 256, 0, stream>>>(xb, wcat, nullptr, qkvu, 4096, 4096, 1024);

  // V^T swizzled tile images (overwrites xb region — dead after GEMM1)
  vtrans<<<dim3(32, 16, 2), 256, 0, stream>>>(qkvu, vtg);

  // key bitmask
  maskbuild<<<64, 64, 0, stream>>>(tt, sl, allowed);

  // attention + gating
  hstu_attn<<<dim3(16, 16, 2), 256, 0, stream>>>(qkvu, vtg, allowed, sl, gated);

  // out = gated @ Wo^T  (M=4096, N=1024, K=1024)
  gemm_bt<0><<<dim3(8, 32), 256, 0, stream>>>(gated, wob, out, nullptr, 4096, 1024, 1024);
}

// Round 7
// 150.513 us; speedup vs baseline: 1.1206x; 1.1206x over previous
//
#include <hip/hip_runtime.h>

// HSTU attention layer: B=2, L=2048, D=1024, H=16, DK=64
// Pipeline: fp32->bf16 cvt (W_q pre-scaled by 0.125*log2e) -> QKVU GEMM ->
// V-transpose (swizzled tile images) -> flash HSTU attention (swapped 32x32x16,
// KVBLK=128, no-max softmax, MFMA row-sum, 2-deep issue-early staging) ->
// gated bf16 -> out GEMM.  XCD-aware block swizzles throughout.

#define L_SEQ 2048

typedef __attribute__((ext_vector_type(8))) short bf16x8;     // MFMA A/B frag
typedef __attribute__((ext_vector_type(8))) unsigned short u16x8;
typedef __attribute__((ext_vector_type(4))) float f32x4;      // 16x16 C/D frag
typedef __attribute__((ext_vector_type(16))) float f32x16;    // 32x32 C/D frag

#if __has_builtin(__builtin_amdgcn_exp2f)
#define EXP2F __builtin_amdgcn_exp2f
#else
#define EXP2F __builtin_exp2f
#endif

__device__ __forceinline__ unsigned short f2bf(float f) {
  union { float f; unsigned u; } c; c.f = f;
  unsigned r = c.u + 0x7FFFu + ((c.u >> 16) & 1u);   // RNE
  return (unsigned short)(r >> 16);
}
__device__ __forceinline__ float bf2f(unsigned short h) {
  union { unsigned u; float f; } c; c.u = ((unsigned)h) << 16;
  return c.f;
}

// async global->LDS, 16B/lane. LDS dest = wave-uniform base + lane*16 (linear).
__device__ __forceinline__ void async16(const void* g, void* l) {
  __builtin_amdgcn_global_load_lds((__attribute__((address_space(1))) void*)g,
                                   (__attribute__((address_space(3))) void*)l,
                                   16, 0, 0);
}

__device__ __forceinline__ unsigned cvtpk_bf16(float lo, float hi) {
  unsigned r; asm("v_cvt_pk_bf16_f32 %0, %1, %2" : "=v"(r) : "v"(lo), "v"(hi));
  return r;
}

// ---------------- fp32 -> bf16 convert (x) ----------------
__global__ __launch_bounds__(256) void cvt_kernel(const float* __restrict__ s,
                                                  unsigned short* __restrict__ d, int n) {
  int i = (blockIdx.x * 256 + threadIdx.x) * 4;
  if (i >= n) return;
  const float4 v = *reinterpret_cast<const float4*>(s + i);
  ushort4 o;
  o.x = f2bf(v.x); o.y = f2bf(v.y); o.z = f2bf(v.z); o.w = f2bf(v.w);
  *reinterpret_cast<ushort4*>(d + i) = o;
}

// ---------------- fused weight convert: Wq(scaled)|Wk|Wv|Wu|Wo -> bf16 ------
__global__ __launch_bounds__(256) void cvtw_kernel(
    const float* __restrict__ wq, const float* __restrict__ wk,
    const float* __restrict__ wv, const float* __restrict__ wu,
    const float* __restrict__ wo, unsigned short* __restrict__ d) {
  const int seg = blockIdx.x >> 10;                  // 1024 blocks per 1M-elem segment
  const float* s = seg == 0 ? wq : seg == 1 ? wk : seg == 2 ? wv : seg == 3 ? wu : wo;
  const float sc = seg == 0 ? 0.18033688011112042f : 1.0f;   // 0.125 * log2(e)
  const int i = ((blockIdx.x & 1023) * 256 + threadIdx.x) * 4;
  const float4 v = *reinterpret_cast<const float4*>(s + i);
  ushort4 o;
  o.x = f2bf(v.x * sc); o.y = f2bf(v.y * sc); o.z = f2bf(v.z * sc); o.w = f2bf(v.w * sc);
  *reinterpret_cast<ushort4*>(d + (size_t)seg * 1048576 + i) = o;
}

// ---------------- key "always-allowed" bitmask: (prompt && j<seqlen) --------
__global__ __launch_bounds__(64) void maskbuild(const int* __restrict__ tt,
                                                const int* __restrict__ sl,
                                                unsigned* __restrict__ allowed) {
  const int b = blockIdx.x >> 5, wv = blockIdx.x & 31;
  const int j = wv * 64 + threadIdx.x;
  const int seqlen = sl[b];
  const unsigned long long m = __ballot((tt[b * L_SEQ + j] < 3) && (j < seqlen));
  if (threadIdx.x == 0) {
    allowed[b * 64 + 2 * wv]     = (unsigned)m;
    allowed[b * 64 + 2 * wv + 1] = (unsigned)(m >> 32);
  }
}

// ---------------- V transpose into swizzled tile images ---------------------
// vtg layout: per (b,h,64-key tile t): 4096 elems (8KB) = the exact LDS image
// attn wants: element (k local, d) at byte d*128 + 16*((k>>3)^(d&7)) + 2*(k&7).
__global__ __launch_bounds__(256) void vtrans(const unsigned short* __restrict__ qkvu,
                                              unsigned short* __restrict__ vtg) {
  __shared__ unsigned short tileb[4096];
  const int t = blockIdx.x, h = blockIdx.y, b = blockIdx.z;
  const size_t rb = (size_t)b * L_SEQ * 4096;
  const int tid = threadIdx.x;
  const int vp = tid & 31, vd0 = (tid >> 5) * 8;
  const int j0 = t * 64;
  const u16x8 g0 = *reinterpret_cast<const u16x8*>(
      qkvu + rb + (size_t)(j0 + 2 * vp) * 4096 + 2048 + h * 64 + vd0);
  const u16x8 g1 = *reinterpret_cast<const u16x8*>(
      qkvu + rb + (size_t)(j0 + 2 * vp + 1) * 4096 + 2048 + h * 64 + vd0);
  #pragma unroll
  for (int e = 0; e < 8; ++e) {
    const int d = vd0 + e;
    const unsigned pk = (unsigned)g0[e] | ((unsigned)g1[e] << 16);
    *reinterpret_cast<unsigned*>((char*)tileb +
        d * 128 + 16 * ((vp >> 2) ^ (d & 7)) + 4 * (vp & 3)) = pk;
  }
  __syncthreads();
  const size_t ob = ((size_t)(b * 16 + h) * 32 + t) * 4096;
  *reinterpret_cast<u16x8*>(vtg + ob + tid * 16) =
      *reinterpret_cast<const u16x8*>(tileb + tid * 16);
  *reinterpret_cast<u16x8*>(vtg + ob + tid * 16 + 8) =
      *reinterpret_cast<const u16x8*>(tileb + tid * 16 + 8);
}

// ---------------- GEMM: C[M][N] = A[M][K] * BT[N][K]^T (m97 structure) -------
// XCD swizzle: logical lin = (d%8)*cpx + d/8 (bijective, nb%8==0).
template<int OUT_BF16>
__global__ __launch_bounds__(256) void gemm_bt(
    const unsigned short* __restrict__ A,
    const unsigned short* __restrict__ BT,
    float* __restrict__ Cf, unsigned short* __restrict__ Cb,
    int M, int N, int K, int cpx, int nbxm, int nbxs)
{
  __shared__ unsigned short As[2][128 * 32];
  __shared__ unsigned short Bs[2][128 * 32];

  const int tid = threadIdx.x;
  const int w = tid >> 6, lane = tid & 63;
  const int lo = lane & 15, hi = lane >> 4;
  const int d = blockIdx.x + gridDim.x * blockIdx.y;
  const int lin = (d & 7) * cpx + (d >> 3);
  const int i0 = (lin >> nbxs) * 128, j0 = (lin & nbxm) * 128;
  const int wr = w >> 1, wc = w & 1;
  const int c0 = w * 2, rsub = lane >> 2, csub = (lane & 3) * 8;

  f32x4 acc[4][4] = {};

  #pragma unroll
  for (int q = 0; q < 2; ++q) {
    const int c = c0 + q;
    async16(A  + (size_t)(i0 + c * 16 + rsub) * K + csub, &As[0][c * 512]);
    async16(BT + (size_t)(j0 + c * 16 + rsub) * K + csub, &Bs[0][c * 512]);
  }
  __syncthreads();

  const int nt = K >> 5;
  for (int t = 0; t < nt; ++t) {
    const int buf = t & 1;
    if (t + 1 < nt) {
      const int k0 = (t + 1) << 5;
      #pragma unroll
      for (int q = 0; q < 2; ++q) {
        const int c = c0 + q;
        async16(A  + (size_t)(i0 + c * 16 + rsub) * K + k0 + csub, &As[buf ^ 1][c * 512]);
        async16(BT + (size_t)(j0 + c * 16 + rsub) * K + k0 + csub, &Bs[buf ^ 1][c * 512]);
      }
    }
    bf16x8 a[4], b[4];
    #pragma unroll
    for (int m = 0; m < 4; ++m)
      a[m] = *reinterpret_cast<const bf16x8*>(&As[buf][(wr * 64 + m * 16 + lo) * 32 + hi * 8]);
    #pragma unroll
    for (int n = 0; n < 4; ++n)
      b[n] = *reinterpret_cast<const bf16x8*>(&Bs[buf][(wc * 64 + n * 16 + lo) * 32 + hi * 8]);
    #pragma unroll
    for (int m = 0; m < 4; ++m)
      #pragma unroll
      for (int n = 0; n < 4; ++n)
        acc[m][n] = __builtin_amdgcn_mfma_f32_16x16x32_bf16(a[m], b[n], acc[m][n], 0, 0, 0);
    __syncthreads();
  }

  #pragma unroll
  for (int m = 0; m < 4; ++m) {
    const int row = i0 + wr * 64 + m * 16 + hi * 4;
    #pragma unroll
    for (int n = 0; n < 4; ++n) {
      const int col = j0 + wc * 64 + n * 16 + lo;
      #pragma unroll
      for (int r = 0; r < 4; ++r) {
        if (OUT_BF16) Cb[(size_t)(row + r) * N + col] = f2bf(acc[m][n][r]);
        else          Cf[(size_t)(row + r) * N + col] = acc[m][n][r];
      }
    }
  }
}

// ---------------- HSTU flash attention + U gating (32x32 swapped, KVBLK=128) -
// grid (16,16,2) XCD-swizzled -> (qt,h,b); 4 waves; wave w owns q-rows
// i0+w*32..+31; lane (c=lane&31) owns q-row i0+w*32+c. No-max softmax.
// 2-deep staging: stage(t+1) issued right after the barrier (race-free),
// vmcnt(0) only at tile end (full body to cover latency).
__global__ __launch_bounds__(256, 2) void hstu_attn(
    const unsigned short* __restrict__ qkvu,
    const unsigned short* __restrict__ vtg,
    const unsigned* __restrict__ allowed,
    const int* __restrict__ slens,
    unsigned short* __restrict__ gated)
{
  // K: [128 key][64 d] row-major, XOR-swizzled: byte = k*128 + 16*((d>>3)^(k&7)) + 2*(d&7)
  // Vl: two 64-key V^T images (8KB each): (k,d) at hv*8192 + d*128 + 16*((kk>>3)^(d&7)) + 2*(kk&7)
  __shared__ unsigned short Kl[2][128 * 64];
  __shared__ unsigned short Vl[2][128 * 64];

  const int dlin = blockIdx.x + (blockIdx.y << 4) + (blockIdx.z << 8);
  const int lin = ((dlin & 7) << 6) | (dlin >> 3);   // XCD swizzle (512%8==0)
  const int qt = lin & 15, h = (lin >> 4) & 15, b = lin >> 8;
  const int i0 = qt * 128;
  const int tid = threadIdx.x, w = tid >> 6, lane = tid & 63;
  const int c = lane & 31, sb = lane >> 5;
  const int seqlen = slens[b];
  const size_t rb = (size_t)b * L_SEQ * 4096;
  const size_t vb = (size_t)(b * 16 + h) * 32 * 4096;
  const int qrow = i0 + w * 32 + c;

  // K staging: pre-swizzled global source, linear LDS dest (4 async16/wave).
  auto stageK = [&](int buf, int t) {
    const int j0 = t * 128;
    #pragma unroll
    for (int q = 0; q < 4; ++q) {
      const int p = w * 4 + q;                       // window 0..15 (8 keys each)
      const int krow = 8 * p + (lane >> 3);
      const int d0 = 8 * ((lane & 7) ^ (lane >> 3)); // inverse of read swizzle
      async16(qkvu + rb + (size_t)(j0 + krow) * 4096 + 1024 + h * 64 + d0,
              &Kl[buf][p * 512]);
    }
  };
  // V^T staging: images already swizzled in global — linear copy (4/wave).
  auto stageV = [&](int buf, int t) {
    #pragma unroll
    for (int q = 0; q < 4; ++q) {
      const int p = w * 4 + q;
      async16(vtg + vb + (size_t)t * 8192 + p * 512 + lane * 8, &Vl[buf][p * 512]);
    }
  };

  const int nt = (seqlen + 127) >> 7;

  stageK(0, 0); stageV(0, 0);

  bf16x8 qf[4];
  #pragma unroll
  for (int kd = 0; kd < 4; ++kd)
    qf[kd] = *reinterpret_cast<const bf16x8*>(
        qkvu + rb + (size_t)qrow * 4096 + h * 64 + kd * 16 + sb * 8);
  const unsigned pmword = allowed[b * 64 + lane];
  const int limb = (qrow < seqlen - 1 ? qrow : seqlen - 1) - 4 * sb;

  union { unsigned u[4]; bf16x8 v; } one_;
  one_.u[0] = one_.u[1] = one_.u[2] = one_.u[3] = 0x3F803F80u;
  const bf16x8 onesv = one_.v;

  f32x16 o0 = {}, o1 = {}, ls = {};

  asm volatile("s_waitcnt vmcnt(0)" ::: "memory");
  __builtin_amdgcn_s_barrier();
  __builtin_amdgcn_sched_barrier(0);

  for (int t = 0; t < nt; ++t) {
    const int buf = t & 1;
    const int j0 = t * 128;
    // stage(t+1) into buf^1: safe — end-of-(t-1) barrier already passed.
    if (t + 1 < nt) { stageK(buf ^ 1, t + 1); stageV(buf ^ 1, t + 1); }

    const char* Kb = (const char*)&Kl[buf][0];
    const char* Vb = (const char*)&Vl[buf][0];
    const bool fast = (j0 + 128 <= seqlen) && (j0 + 127 <= i0 + w * 32);

    // per 32-key sub-block: QK -> exp/mask -> pack -> PV (keeps VGPR low,
    // interleaves VALU with MFMA)
    #pragma unroll
    for (int z = 0; z < 4; ++z) {
      f32x16 s = {};
      __builtin_amdgcn_s_setprio(1);
      #pragma unroll
      for (int kd = 0; kd < 4; ++kd) {
        const bf16x8 kf = *reinterpret_cast<const bf16x8*>(
            Kb + (32 * z + c) * 128 + (((2 * kd + sb) ^ (c & 7)) << 4));
        s = __builtin_amdgcn_mfma_f32_32x32x16_bf16(kf, qf[kd], s, 0, 0, 0);
      }
      __builtin_amdgcn_s_setprio(0);

      if (fast) {
        #pragma unroll
        for (int r = 0; r < 16; ++r) s[r] = EXP2F(s[r]);
      } else {
        const unsigned pmz = __builtin_amdgcn_readlane(pmword, 4 * t + z);
        const int lim = limb - j0 - 32 * z;
        const unsigned cm = lim < 0 ? 0u : (lim >= 31 ? ~0u : ((2u << lim) - 1u));
        const unsigned al = (pmz >> (4 * sb)) | cm;
        #pragma unroll
        for (int r = 0; r < 16; ++r) {
          const int kc = (r & 3) + 8 * (r >> 2);     // key pos (minus 4*sb)
          const float p = EXP2F(s[r]);
          s[r] = ((al >> kc) & 1) ? p : 0.f;
        }
      }

      // pack: 8 cvt_pk + 4 permlane32_swap -> two B-frags (keys 32z+0..15, +16..31)
      bf16x8 pfA, pfB;
      {
        unsigned U0, U1, W0, W1;
        U0 = cvtpk_bf16(s[0], s[1]);  U1 = cvtpk_bf16(s[2], s[3]);
        W0 = cvtpk_bf16(s[4], s[5]);  W1 = cvtpk_bf16(s[6], s[7]);
        asm("v_permlane32_swap_b32 %0, %1" : "+v"(U0), "+v"(W0));
        asm("v_permlane32_swap_b32 %0, %1" : "+v"(U1), "+v"(W1));
        union { unsigned u[4]; bf16x8 v; } pu;
        pu.u[0] = U0; pu.u[1] = U1; pu.u[2] = W0; pu.u[3] = W1; pfA = pu.v;
        U0 = cvtpk_bf16(s[8], s[9]);   U1 = cvtpk_bf16(s[10], s[11]);
        W0 = cvtpk_bf16(s[12], s[13]); W1 = cvtpk_bf16(s[14], s[15]);
        asm("v_permlane32_swap_b32 %0, %1" : "+v"(U0), "+v"(W0));
        asm("v_permlane32_swap_b32 %0, %1" : "+v"(U1), "+v"(W1));
        pu.u[0] = U0; pu.u[1] = U1; pu.u[2] = W0; pu.u[3] = W1; pfB = pu.v;
      }

      // PV: key groups g = 2z, 2z+1; V image half hv = z>>1, kpl = 2*(z&1)+{0,1}
      {
        const char* Vh = Vb + (z >> 1) * 8192 + c * 128;
        const int swA = ((4 * (z & 1) + sb) ^ (c & 7)) << 4;
        const int swB = ((4 * (z & 1) + 2 + sb) ^ (c & 7)) << 4;
        const bf16x8 va0 = *reinterpret_cast<const bf16x8*>(Vh + swA);
        const bf16x8 va1 = *reinterpret_cast<const bf16x8*>(Vh + 4096 + swA);
        const bf16x8 vb0 = *reinterpret_cast<const bf16x8*>(Vh + swB);
        const bf16x8 vb1 = *reinterpret_cast<const bf16x8*>(Vh + 4096 + swB);
        __builtin_amdgcn_s_setprio(1);
        o0 = __builtin_amdgcn_mfma_f32_32x32x16_bf16(va0, pfA, o0, 0, 0, 0);
        o1 = __builtin_amdgcn_mfma_f32_32x32x16_bf16(va1, pfA, o1, 0, 0, 0);
        ls = __builtin_amdgcn_mfma_f32_32x32x16_bf16(onesv, pfA, ls, 0, 0, 0);
        o0 = __builtin_amdgcn_mfma_f32_32x32x16_bf16(vb0, pfB, o0, 0, 0, 0);
        o1 = __builtin_amdgcn_mfma_f32_32x32x16_bf16(vb1, pfB, o1, 0, 0, 0);
        ls = __builtin_amdgcn_mfma_f32_32x32x16_bf16(onesv, pfB, ls, 0, 0, 0);
        __builtin_amdgcn_s_setprio(0);
      }
    }

    // stage(t+1) had the whole tile body to land
    asm volatile("s_waitcnt vmcnt(0)" ::: "memory");
    __builtin_amdgcn_s_barrier();
    __builtin_amdgcn_sched_barrier(0);
  }

  // ---- epilogue: gated = O/l * U ; O^T row d = n*32+(r&3)+8*(r>>2)+4sb, col q ----
  const float rin = 1.0f / ls[0];
  #pragma unroll
  for (int n = 0; n < 2; ++n) {
    const f32x16 o = n ? o1 : o0;
    #pragma unroll
    for (int rq = 0; rq < 4; ++rq) {
      const int d0 = n * 32 + 8 * rq + 4 * sb;
      const ushort4 uu = *reinterpret_cast<const ushort4*>(
          qkvu + rb + (size_t)qrow * 4096 + 3072 + h * 64 + d0);
      ushort4 g;
      g.x = f2bf(o[4 * rq + 0] * rin * bf2f(uu.x));
      g.y = f2bf(o[4 * rq + 1] * rin * bf2f(uu.y));
      g.z = f2bf(o[4 * rq + 2] * rin * bf2f(uu.z));
      g.w = f2bf(o[4 * rq + 3] * rin * bf2f(uu.w));
      *reinterpret_cast<ushort4*>(
          gated + (size_t)(b * L_SEQ + qrow) * 1024 + h * 64 + d0) = g;
    }
  }
}

// ---------------- launch ----------------
extern "C" void kernel_launch(void* const* d_in, const int* in_sizes, int n_in,
                              void* d_out, int out_size, void* d_ws, size_t ws_size,
                              hipStream_t stream) {
  const float* x  = (const float*)d_in[0];
  const int* tt   = (const int*)d_in[1];
  const int* sl   = (const int*)d_in[2];
  const float* Wq = (const float*)d_in[3];
  const float* Wk = (const float*)d_in[4];
  const float* Wv = (const float*)d_in[5];
  const float* Wu = (const float*)d_in[6];
  const float* Wo = (const float*)d_in[7];
  float* out = (float*)d_out;

  // ws layout: allowed[512B] | xb(8MB, ->vtg after GEMM1) | wcat(8MB) |
  //            wob(2MB) | qkvu(32MB) | gated(8MB)
  unsigned* allowed     = (unsigned*)d_ws;
  unsigned short* xb    = (unsigned short*)d_ws + 256;
  unsigned short* wcat  = xb    + (size_t)4096 * 1024;
  unsigned short* wob   = wcat  + (size_t)4096 * 1024;
  unsigned short* qkvu  = wob   + (size_t)1024 * 1024;
  unsigned short* gated = qkvu  + (size_t)4096 * 4096;
  unsigned short* vtg   = xb;    // 8MB, reuses xb AFTER GEMM1 consumed it

  cvt_kernel<<<4096, 256, 0, stream>>>(x, xb, 4096 * 1024);
  cvtw_kernel<<<5120, 256, 0, stream>>>(Wq, Wk, Wv, Wu, Wo, wcat);

  // QKVU = x @ [Wq'|Wk|Wv|Wu]^T   (M=4096, N=4096, K=1024), 1024 blocks
  gemm_bt<1><<<dim3(32, 32), 256, 0, stream>>>(xb, wcat, nullptr, qkvu,
                                               4096, 4096, 1024, 128, 31, 5);

  // V^T swizzled tile images (overwrites xb region — dead after GEMM1)
  vtrans<<<dim3(32, 16, 2), 256, 0, stream>>>(qkvu, vtg);

  // key bitmask
  maskbuild<<<64, 64, 0, stream>>>(tt, sl, allowed);

  // attention + gating
  hstu_attn<<<dim3(16, 16, 2), 256, 0, stream>>>(qkvu, vtg, allowed, sl, gated);

  // out = gated @ Wo^T  (M=4096, N=1024, K=1024), 256 blocks
  gemm_bt<0><<<dim3(8, 32), 256, 0, stream>>>(gated, wob, out, nullptr,
                                              4096, 1024, 1024, 32, 7, 3);
}